// Round 1
// baseline (54798.181 us; speedup 1.0000x reference)
//
#include <hip/hip_runtime.h>
#include <math.h>

#define BBATCH 4
#define SSEQ   2048
#define DMODEL 768
#define NHEAD  12
#define DHEAD  64
#define DFFN   3072
#define NLAYER 12
#define NEGV   (-1e9f)
#define QSCALE 0.125f

// ---------------- block reduction helper (256 threads) ----------------
__device__ __forceinline__ float block_sum_256(float v, float* red) {
  int t = threadIdx.x;
  red[t] = v;
  __syncthreads();
#pragma unroll
  for (int s = 128; s > 0; s >>= 1) {
    if (t < s) red[t] += red[t + s];
    __syncthreads();
  }
  float r = red[0];
  __syncthreads();
  return r;
}

// ---------------- embeddings + LN ----------------
__global__ __launch_bounds__(256) void embed_ln_kernel(
    const int* __restrict__ ids, const float* __restrict__ ew,
    const float* __restrict__ ep, const float* __restrict__ lns,
    const float* __restrict__ lnb, float* __restrict__ h) {
  __shared__ float red[256];
  int tok = blockIdx.x;                 // b*S + s
  int s = tok % SSEQ;
  int id = ids[tok];
  const float* wp = ew + (size_t)id * DMODEL;
  const float* pp = ep + (size_t)s * DMODEL;
  float vals[3];
  float sum = 0.f;
#pragma unroll
  for (int i = 0; i < 3; i++) {
    int d = threadIdx.x + i * 256;
    vals[i] = wp[d] + pp[d];
    sum += vals[i];
  }
  float mean = block_sum_256(sum, red) * (1.0f / DMODEL);
  float vsum = 0.f;
#pragma unroll
  for (int i = 0; i < 3; i++) { float df = vals[i] - mean; vsum += df * df; }
  float var = block_sum_256(vsum, red) * (1.0f / DMODEL);
  float inv = rsqrtf(var + 1e-5f);
#pragma unroll
  for (int i = 0; i < 3; i++) {
    int d = threadIdx.x + i * 256;
    h[(size_t)tok * DMODEL + d] = (vals[i] - mean) * inv * lns[d] + lnb[d];
  }
}

// ---------------- h = LN(h + delta) ----------------
__global__ __launch_bounds__(256) void add_ln_kernel(
    float* __restrict__ h, const float* __restrict__ delta,
    const float* __restrict__ lns, const float* __restrict__ lnb) {
  __shared__ float red[256];
  size_t base = (size_t)blockIdx.x * DMODEL;
  float vals[3];
  float sum = 0.f;
#pragma unroll
  for (int i = 0; i < 3; i++) {
    int d = threadIdx.x + i * 256;
    vals[i] = h[base + d] + delta[base + d];
    sum += vals[i];
  }
  float mean = block_sum_256(sum, red) * (1.0f / DMODEL);
  float vsum = 0.f;
#pragma unroll
  for (int i = 0; i < 3; i++) { float df = vals[i] - mean; vsum += df * df; }
  float var = block_sum_256(vsum, red) * (1.0f / DMODEL);
  float inv = rsqrtf(var + 1e-5f);
#pragma unroll
  for (int i = 0; i < 3; i++) {
    int d = threadIdx.x + i * 256;
    h[base + d] = (vals[i] - mean) * inv * lns[d] + lnb[d];
  }
}

// ---------------- generic fp32 GEMM: C[M,N] = A[M,K]@W[K,N] + bias ----------------
// 128x128 tile, BK=16, 256 threads, 8x8 per thread. EPI: 0=bias, 1=bias+gelu(exact)
template <int EPI>
__global__ __launch_bounds__(256) void gemm_kernel(
    const float* __restrict__ A, const float* __restrict__ Wt,
    const float* __restrict__ bias, float* __restrict__ C,
    int M, int N, int K) {
  __shared__ float As[16][128];
  __shared__ float Bs[16][128];
  int m0 = blockIdx.x * 128;
  int n0 = blockIdx.y * 128;
  int t = threadIdx.x;
  int tx = t & 15;
  int ty = t >> 4;
  float acc[8][8];
#pragma unroll
  for (int i = 0; i < 8; i++)
#pragma unroll
    for (int j = 0; j < 8; j++) acc[i][j] = 0.f;

  for (int k0 = 0; k0 < K; k0 += 16) {
#pragma unroll
    for (int i = 0; i < 2; i++) {
      int f = t + i * 256;
      int r = f >> 2, q4 = f & 3;
      float4 av = *(const float4*)(A + (size_t)(m0 + r) * K + k0 + q4 * 4);
      As[q4 * 4 + 0][r] = av.x;
      As[q4 * 4 + 1][r] = av.y;
      As[q4 * 4 + 2][r] = av.z;
      As[q4 * 4 + 3][r] = av.w;
      int kk = f >> 5, seg = f & 31;
      *(float4*)(&Bs[kk][seg * 4]) =
          *(const float4*)(Wt + (size_t)(k0 + kk) * N + n0 + seg * 4);
    }
    __syncthreads();
#pragma unroll
    for (int k = 0; k < 16; k++) {
      float a[8], b[8];
      *(float4*)(a)     = *(float4*)(&As[k][ty * 8]);
      *(float4*)(a + 4) = *(float4*)(&As[k][ty * 8 + 4]);
      *(float4*)(b)     = *(float4*)(&Bs[k][tx * 8]);
      *(float4*)(b + 4) = *(float4*)(&Bs[k][tx * 8 + 4]);
#pragma unroll
      for (int i = 0; i < 8; i++)
#pragma unroll
        for (int j = 0; j < 8; j++) acc[i][j] = fmaf(a[i], b[j], acc[i][j]);
    }
    __syncthreads();
  }

#pragma unroll
  for (int i = 0; i < 8; i++) {
    size_t m = (size_t)(m0 + ty * 8 + i);
    float outv[8];
#pragma unroll
    for (int j = 0; j < 8; j++) {
      int n = n0 + tx * 8 + j;
      float v = acc[i][j] + bias[n];
      if (EPI == 1) v = 0.5f * v * (1.f + erff(v * 0.70710678118654752f));
      outv[j] = v;
    }
    *(float4*)(C + m * N + n0 + tx * 8)     = *(float4*)(outv);
    *(float4*)(C + m * N + n0 + tx * 8 + 4) = *(float4*)(outv + 4);
  }
}

// ---------------- local (banded) attention, flash-style streaming ----------------
// grid = B*H*8*8 blocks; block handles (b,h,chunk n, 32-query group qg)
__global__ __launch_bounds__(256) void local_attn_kernel(
    const float* __restrict__ q, const float* __restrict__ k,
    const float* __restrict__ v, const float* __restrict__ amask,
    float* __restrict__ O) {
  int x = blockIdx.x;
  int qg = x & 7;
  int n  = (x >> 3) & 7;
  int hh = (x >> 6) % NHEAD;
  int bb = (x >> 6) / NHEAD;
  int q0 = n * 256 + qg * 32;           // global pos of first query row

  __shared__ float qs[32][68];
  __shared__ float ks[64][68];
  __shared__ float vs[64][68];
  __shared__ float sc[32][68];
  __shared__ float mrun[32], lrun[32], corr[32], pg[32];
  __shared__ float k0s[64], v0s[64];

  int t = threadIdx.x;
  int qi = t >> 3;
  int g  = t & 7;

  // load 32 query rows (head slice)
#pragma unroll
  for (int i = 0; i < 2; i++) {
    int f = t + i * 256;
    int r = f >> 4, seg = f & 15;
    *(float4*)(&qs[r][seg * 4]) = *(const float4*)(
        q + ((size_t)(bb * SSEQ + q0 + r)) * DMODEL + hh * DHEAD + seg * 4);
  }
  if (t < 32) { mrun[t] = -INFINITY; lrun[t] = 0.f; }
  float o[8];
#pragma unroll
  for (int i = 0; i < 8; i++) o[i] = 0.f;
  __syncthreads();

  for (int tile = 0; tile < 12; tile++) {
    int jp0 = (n - 1) * 256 + tile * 64;
    if (jp0 + 63 < 0 || jp0 >= SSEQ) continue;                 // fully OOB
    if (jp0 + 63 < q0 - 256 || jp0 > q0 + 31 + 256) continue;  // outside band

    // stage k/v tile (64 keys x 64 dims)
#pragma unroll
    for (int i = 0; i < 4; i++) {
      int f = t + i * 256;
      int r = f >> 4, seg = f & 15;
      int jp = jp0 + r;
      float4 kv = make_float4(0.f, 0.f, 0.f, 0.f);
      float4 vv = make_float4(0.f, 0.f, 0.f, 0.f);
      if (jp >= 0 && jp < SSEQ) {
        size_t base = ((size_t)(bb * SSEQ + jp)) * DMODEL + hh * DHEAD + seg * 4;
        kv = *(const float4*)(k + base);
        vv = *(const float4*)(v + base);
      }
      *(float4*)(&ks[r][seg * 4]) = kv;
      *(float4*)(&vs[r][seg * 4]) = vv;
    }
    __syncthreads();

    // scores: thread -> (qi, keys j = jj*8 + g)
    float acc8[8];
#pragma unroll
    for (int jj = 0; jj < 8; jj++) acc8[jj] = 0.f;
#pragma unroll
    for (int c4 = 0; c4 < 16; c4++) {
      float4 qv = *(float4*)(&qs[qi][c4 * 4]);
#pragma unroll
      for (int jj = 0; jj < 8; jj++) {
        float4 kv = *(float4*)(&ks[jj * 8 + g][c4 * 4]);
        acc8[jj] = fmaf(qv.x, kv.x, acc8[jj]);
        acc8[jj] = fmaf(qv.y, kv.y, acc8[jj]);
        acc8[jj] = fmaf(qv.z, kv.z, acc8[jj]);
        acc8[jj] = fmaf(qv.w, kv.w, acc8[jj]);
      }
    }
    int qpos = q0 + qi;
#pragma unroll
    for (int jj = 0; jj < 8; jj++) {
      int j = jj * 8 + g;
      int jp = jp0 + j;
      int rel = jp - qpos;
      bool ok = (jp >= 0) && (jp < SSEQ) && (jp != 0) && (rel <= 256) && (rel >= -256);
      if (ok) ok = amask[bb * SSEQ + jp] > 0.5f;
      sc[qi][j] = ok ? acc8[jj] * QSCALE : NEGV;
    }
    __syncthreads();

    // online softmax state update (one thread per query row)
    if (t < 32) {
      float mold = mrun[t];
      float mx = mold;
      for (int j = 0; j < 64; j++) mx = fmaxf(mx, sc[t][j]);
      float cr = expf(mold - mx);
      float ssum = 0.f;
      for (int j = 0; j < 64; j++) {
        float e = expf(sc[t][j] - mx);
        sc[t][j] = e;
        ssum += e;
      }
      mrun[t] = mx;
      lrun[t] = lrun[t] * cr + ssum;
      corr[t] = cr;
    }
    __syncthreads();

    // P@V accumulate: thread owns (qi, dims g*8..g*8+7)
    {
      float cr = corr[qi];
#pragma unroll
      for (int i = 0; i < 8; i++) o[i] *= cr;
      for (int j = 0; j < 64; j++) {
        float p = sc[qi][j];
        float4 v0 = *(float4*)(&vs[j][g * 8]);
        float4 v1 = *(float4*)(&vs[j][g * 8 + 4]);
        o[0] = fmaf(p, v0.x, o[0]);
        o[1] = fmaf(p, v0.y, o[1]);
        o[2] = fmaf(p, v0.z, o[2]);
        o[3] = fmaf(p, v0.w, o[3]);
        o[4] = fmaf(p, v1.x, o[4]);
        o[5] = fmaf(p, v1.y, o[5]);
        o[6] = fmaf(p, v1.z, o[6]);
        o[7] = fmaf(p, v1.w, o[7]);
      }
    }
    __syncthreads();
  }

  // global token-0 key column (joint softmax, never masked)
  if (t < 64) {
    size_t base = ((size_t)(bb * SSEQ)) * DMODEL + hh * DHEAD + t;
    k0s[t] = k[base];
    v0s[t] = v[base];
  }
  __syncthreads();
  if (t < 32) {
    float gs = 0.f;
    for (int d = 0; d < 64; d++) gs = fmaf(qs[t][d], k0s[d], gs);
    gs *= QSCALE;
    float mold = mrun[t];
    float mx = fmaxf(mold, gs);
    float cr = expf(mold - mx);
    float pgv = expf(gs - mx);
    lrun[t] = lrun[t] * cr + pgv;
    corr[t] = cr;
    pg[t] = pgv;
  }
  __syncthreads();
  {
    float cr = corr[qi];
    float pgv = pg[qi];
    float inv = 1.0f / lrun[qi];
    float out8[8];
#pragma unroll
    for (int i = 0; i < 8; i++) out8[i] = (o[i] * cr + pgv * v0s[g * 8 + i]) * inv;
    size_t base = ((size_t)(bb * SSEQ + q0 + qi)) * DMODEL + hh * DHEAD + g * 8;
    *(float4*)(O + base)     = *(float4*)(out8);
    *(float4*)(O + base + 4) = *(float4*)(out8 + 4);
  }
}

// ---------------- global token-0 query attention: grid = B*H ----------------
__global__ __launch_bounds__(256) void global_attn_kernel(
    const float* __restrict__ qg, const float* __restrict__ kg,
    const float* __restrict__ vg, const float* __restrict__ amask,
    float* __restrict__ O) {
  int bb = blockIdx.x / NHEAD;
  int hh = blockIdx.x % NHEAD;
  __shared__ float p[SSEQ];
  __shared__ float qv[64];
  __shared__ float red[256];
  __shared__ float part[4][64];
  int t = threadIdx.x;
  if (t < 64) qv[t] = qg[(bb * NHEAD + hh) * 64 + t];
  __syncthreads();
  float mx = -INFINITY;
#pragma unroll
  for (int i = 0; i < 8; i++) {
    int s = t + i * 256;
    const float* kp = kg + ((size_t)(bb * SSEQ + s)) * DMODEL + hh * DHEAD;
    float acc = 0.f;
    for (int d = 0; d < 64; d += 4) {
      float4 kv = *(const float4*)(kp + d);
      acc = fmaf(qv[d], kv.x, acc);
      acc = fmaf(qv[d + 1], kv.y, acc);
      acc = fmaf(qv[d + 2], kv.z, acc);
      acc = fmaf(qv[d + 3], kv.w, acc);
    }
    if (!(amask[bb * SSEQ + s] > 0.5f)) acc = NEGV;
    p[s] = acc;
    mx = fmaxf(mx, acc);
  }
  red[t] = mx;
  __syncthreads();
  for (int sft = 128; sft > 0; sft >>= 1) {
    if (t < sft) red[t] = fmaxf(red[t], red[t + sft]);
    __syncthreads();
  }
  mx = red[0];
  __syncthreads();
  float lsum = 0.f;
#pragma unroll
  for (int i = 0; i < 8; i++) {
    int s = t + i * 256;
    float e = expf(p[s] - mx);
    p[s] = e;
    lsum += e;
  }
  float l = block_sum_256(lsum, red);
  int d = t & 63, stripe = t >> 6;
  float acc = 0.f;
  for (int s = stripe * 512; s < stripe * 512 + 512; s++) {
    acc = fmaf(p[s], vg[((size_t)(bb * SSEQ + s)) * DMODEL + hh * DHEAD + d], acc);
  }
  part[stripe][d] = acc;
  __syncthreads();
  if (t < 64) {
    float sum = part[0][t] + part[1][t] + part[2][t] + part[3][t];
    O[((size_t)(bb * SSEQ)) * DMODEL + hh * DHEAD + t] = sum / l;
  }
}

// ---------------- tiny row-vector x matrix: y[b,:] = act((x_b @ W + bias)*scl) ----------------
// grid = B * (N/256); act: 0=none, 1=tanh
__global__ __launch_bounds__(256) void rowvec_mat_kernel(
    const float* __restrict__ x, size_t xstride, const float* __restrict__ Wt,
    const float* __restrict__ bias, float* __restrict__ y, int K, int N,
    float scl, int act) {
  int ncg = N >> 8;
  int bb = blockIdx.x / ncg;
  int cg = blockIdx.x % ncg;
  int j = cg * 256 + threadIdx.x;
  const float* xr = x + (size_t)bb * xstride;
  float acc = bias[j];
  for (int kk = 0; kk < K; kk++) acc = fmaf(xr[kk], Wt[(size_t)kk * N + j], acc);
  acc *= scl;
  if (act == 1) acc = tanhf(acc);
  y[(size_t)bb * N + j] = acc;
}

// ---------------- final head: cls -> mc -> softmax(16) ----------------
__global__ __launch_bounds__(256) void head_kernel(
    const float* __restrict__ pooled, const float* __restrict__ clsW,
    const float* __restrict__ clsb, const float* __restrict__ mcW,
    const float* __restrict__ mcb, float* __restrict__ out) {
  __shared__ float lg[8];
  __shared__ float o16[16];
  int t = threadIdx.x;
  if (t < 8) {
    int bb = t >> 1, cc2 = t & 1;
    float acc = clsb[cc2];
    for (int kk = 0; kk < DMODEL; kk++)
      acc = fmaf(pooled[bb * DMODEL + kk], clsW[kk * 2 + cc2], acc);
    lg[t] = acc;
  }
  __syncthreads();
  if (t < 16) {
    float acc = mcb[t];
    for (int i = 0; i < 8; i++) acc = fmaf(lg[i], mcW[i * 16 + t], acc);
    o16[t] = acc;
  }
  __syncthreads();
  if (t == 0) {
    float mx = o16[0];
    for (int i = 1; i < 16; i++) mx = fmaxf(mx, o16[i]);
    float sum = 0.f;
    float e[16];
    for (int i = 0; i < 16; i++) { e[i] = expf(o16[i] - mx); sum += e[i]; }
    for (int i = 0; i < 16; i++) out[i] = e[i] / sum;
  }
}

// ---------------- host launcher ----------------
extern "C" void kernel_launch(void* const* d_in, const int* in_sizes, int n_in,
                              void* d_out, int out_size, void* d_ws, size_t ws_size,
                              hipStream_t stream) {
  (void)in_sizes; (void)n_in; (void)out_size; (void)ws_size;
  const int*   ids      = (const int*)d_in[0];
  const float* amask    = (const float*)d_in[1];
  const float* emb_word = (const float*)d_in[2];
  const float* emb_pos  = (const float*)d_in[3];
  const float* ln_emb_s = (const float*)d_in[4];
  const float* ln_emb_b = (const float*)d_in[5];
  const float* Wq  = (const float*)d_in[6];
  const float* Wk  = (const float*)d_in[7];
  const float* Wv  = (const float*)d_in[8];
  const float* Wqg = (const float*)d_in[9];
  const float* Wkg = (const float*)d_in[10];
  const float* Wvg = (const float*)d_in[11];
  const float* Wo  = (const float*)d_in[12];
  const float* bq  = (const float*)d_in[13];
  const float* bk  = (const float*)d_in[14];
  const float* bv  = (const float*)d_in[15];
  const float* bqg = (const float*)d_in[16];
  const float* bkg = (const float*)d_in[17];
  const float* bvg = (const float*)d_in[18];
  const float* bo  = (const float*)d_in[19];
  const float* ln1_s = (const float*)d_in[20];
  const float* ln1_b = (const float*)d_in[21];
  const float* Wi  = (const float*)d_in[22];
  const float* bi  = (const float*)d_in[23];
  const float* Wf  = (const float*)d_in[24];
  const float* bf  = (const float*)d_in[25];
  const float* ln2_s = (const float*)d_in[26];
  const float* ln2_b = (const float*)d_in[27];
  const float* pooler_W = (const float*)d_in[28];
  const float* pooler_b = (const float*)d_in[29];
  const float* cls_W = (const float*)d_in[30];
  const float* cls_b = (const float*)d_in[31];
  const float* mc_W  = (const float*)d_in[32];
  const float* mc_b  = (const float*)d_in[33];
  float* out = (float*)d_out;

  float* ws = (float*)d_ws;
  const size_t NT = (size_t)BBATCH * SSEQ;   // 8192 tokens
  const size_t TD = NT * DMODEL;             // 6291456 floats per panel
  float* h  = ws;
  float* P0 = ws + TD;
  float* P1 = ws + 2 * TD;
  float* P2 = ws + 3 * TD;
  float* P3 = ws + 4 * TD;
  float* P4 = ws + 5 * TD;
  float* qgb    = ws + 6 * TD;               // [B, H*DH] = [4,768]
  float* pooled = qgb + BBATCH * DMODEL;     // [4,768]

  embed_ln_kernel<<<(int)NT, 256, 0, stream>>>(ids, emb_word, emb_pos,
                                               ln_emb_s, ln_emb_b, h);

  dim3 gDD(NT / 128, DMODEL / 128);   // (64, 6)
  dim3 gF1(NT / 128, DFFN / 128);     // (64, 24)

  for (int l = 0; l < NLAYER; l++) {
    const size_t wd = (size_t)l * DMODEL * DMODEL;
    // local projections q,k,v  ([B,S,D] layout; head slices via stride)
    gemm_kernel<0><<<gDD, 256, 0, stream>>>(h, Wq + wd, bq + l * DMODEL, P0, (int)NT, DMODEL, DMODEL);
    gemm_kernel<0><<<gDD, 256, 0, stream>>>(h, Wk + wd, bk + l * DMODEL, P1, (int)NT, DMODEL, DMODEL);
    gemm_kernel<0><<<gDD, 256, 0, stream>>>(h, Wv + wd, bv + l * DMODEL, P2, (int)NT, DMODEL, DMODEL);
    // banded local attention (+ global token-0 key column), writes O = P3
    local_attn_kernel<<<BBATCH * NHEAD * 8 * 8, 256, 0, stream>>>(P0, P1, P2, amask, P3);
    // global projections (q,k dead -> reuse P0,P1)
    gemm_kernel<0><<<gDD, 256, 0, stream>>>(h, Wkg + wd, bkg + l * DMODEL, P0, (int)NT, DMODEL, DMODEL);
    gemm_kernel<0><<<gDD, 256, 0, stream>>>(h, Wvg + wd, bvg + l * DMODEL, P1, (int)NT, DMODEL, DMODEL);
    rowvec_mat_kernel<<<BBATCH * 3, 256, 0, stream>>>(h, (size_t)SSEQ * DMODEL,
        Wqg + wd, bqg + l * DMODEL, qgb, DMODEL, DMODEL, QSCALE, 0);
    // global token-0 full attention overwrites O row s=0
    global_attn_kernel<<<BBATCH * NHEAD, 256, 0, stream>>>(qgb, P0, P1, amask, P3);
    // output projection + residual LN
    gemm_kernel<0><<<gDD, 256, 0, stream>>>(P3, Wo + wd, bo + l * DMODEL, P2, (int)NT, DMODEL, DMODEL);
    add_ln_kernel<<<(int)NT, 256, 0, stream>>>(h, P2, ln1_s + l * DMODEL, ln1_b + l * DMODEL);
    // FFN: mid = gelu(h@Wi+bi) spans P0..P3 (all dead), out -> P4
    gemm_kernel<1><<<gF1, 256, 0, stream>>>(h, Wi + (size_t)l * DMODEL * DFFN,
                                            bi + l * DFFN, P0, (int)NT, DFFN, DMODEL);
    gemm_kernel<0><<<gDD, 256, 0, stream>>>(P0, Wf + (size_t)l * DFFN * DMODEL,
                                            bf + l * DMODEL, P4, (int)NT, DMODEL, DFFN);
    add_ln_kernel<<<(int)NT, 256, 0, stream>>>(h, P4, ln2_s + l * DMODEL, ln2_b + l * DMODEL);
  }

  // pooler (tanh) on token 0 of each batch row
  rowvec_mat_kernel<<<BBATCH * 3, 256, 0, stream>>>(h, (size_t)SSEQ * DMODEL,
      pooler_W, pooler_b, pooled, DMODEL, DMODEL, 1.0f, 1);
  // cls -> mc -> softmax
  head_kernel<<<1, 256, 0, stream>>>(pooled, cls_W, cls_b, mc_W, mc_b, out);
}

// Round 2
// 13473.415 us; speedup vs baseline: 4.0671x; 4.0671x over previous
//
#include <hip/hip_runtime.h>
#include <hip/hip_bf16.h>
#include <math.h>

#define BBATCH 4
#define SSEQ   2048
#define DMODEL 768
#define NHEAD  12
#define DHEAD  64
#define DFFN   3072
#define NLAYER 12
#define NEGV   (-1e9f)
#define QSCALE 0.125f

typedef unsigned short u16;
typedef __attribute__((ext_vector_type(8))) short bf16x8;
typedef __attribute__((ext_vector_type(4))) float f32x4;

__device__ __forceinline__ u16 f2bf(float x) {
  __hip_bfloat16 h = __float2bfloat16(x);
  union { __hip_bfloat16 h; u16 u; } c;
  c.h = h;
  return c.u;
}

__device__ __forceinline__ void load_lds16(const void* g, void* l) {
  __builtin_amdgcn_global_load_lds(
      (const __attribute__((address_space(1))) unsigned int*)g,
      (__attribute__((address_space(3))) unsigned int*)l, 16, 0, 0);
}

// ---------------- block reduction helper (256 threads) ----------------
__device__ __forceinline__ float block_sum_256(float v, float* red) {
  int t = threadIdx.x;
  red[t] = v;
  __syncthreads();
#pragma unroll
  for (int s = 128; s > 0; s >>= 1) {
    if (t < s) red[t] += red[t + s];
    __syncthreads();
  }
  float r = red[0];
  __syncthreads();
  return r;
}

// ---------------- embeddings + LN (dual write fp32 + bf16) ----------------
__global__ __launch_bounds__(256) void embed_ln_kernel(
    const int* __restrict__ ids, const float* __restrict__ ew,
    const float* __restrict__ ep, const float* __restrict__ lns,
    const float* __restrict__ lnb, float* __restrict__ h,
    u16* __restrict__ hb) {
  __shared__ float red[256];
  int tok = blockIdx.x;
  int s = tok % SSEQ;
  int id = ids[tok];
  const float* wp = ew + (size_t)id * DMODEL;
  const float* pp = ep + (size_t)s * DMODEL;
  float vals[3];
  float sum = 0.f;
#pragma unroll
  for (int i = 0; i < 3; i++) {
    int d = threadIdx.x + i * 256;
    vals[i] = wp[d] + pp[d];
    sum += vals[i];
  }
  float mean = block_sum_256(sum, red) * (1.0f / DMODEL);
  float vsum = 0.f;
#pragma unroll
  for (int i = 0; i < 3; i++) { float df = vals[i] - mean; vsum += df * df; }
  float var = block_sum_256(vsum, red) * (1.0f / DMODEL);
  float inv = rsqrtf(var + 1e-5f);
#pragma unroll
  for (int i = 0; i < 3; i++) {
    int d = threadIdx.x + i * 256;
    float o = (vals[i] - mean) * inv * lns[d] + lnb[d];
    h[(size_t)tok * DMODEL + d] = o;
    hb[(size_t)tok * DMODEL + d] = f2bf(o);
  }
}

// ---------------- h = LN(h + delta), dual write ----------------
__global__ __launch_bounds__(256) void add_ln_kernel(
    float* __restrict__ h, const float* __restrict__ delta,
    const float* __restrict__ lns, const float* __restrict__ lnb,
    u16* __restrict__ hb) {
  __shared__ float red[256];
  size_t base = (size_t)blockIdx.x * DMODEL;
  float vals[3];
  float sum = 0.f;
#pragma unroll
  for (int i = 0; i < 3; i++) {
    int d = threadIdx.x + i * 256;
    vals[i] = h[base + d] + delta[base + d];
    sum += vals[i];
  }
  float mean = block_sum_256(sum, red) * (1.0f / DMODEL);
  float vsum = 0.f;
#pragma unroll
  for (int i = 0; i < 3; i++) { float df = vals[i] - mean; vsum += df * df; }
  float var = block_sum_256(vsum, red) * (1.0f / DMODEL);
  float inv = rsqrtf(var + 1e-5f);
#pragma unroll
  for (int i = 0; i < 3; i++) {
    int d = threadIdx.x + i * 256;
    float o = (vals[i] - mean) * inv * lns[d] + lnb[d];
    h[base + d] = o;
    hb[base + d] = f2bf(o);
  }
}

// ---------------- transpose + fp32->bf16 convert: Wt[N,K] <- W[K,N] ----------------
__global__ __launch_bounds__(256) void convt_kernel(
    const float* __restrict__ W, u16* __restrict__ Wt, int K, int N) {
  __shared__ float tl[64][65];
  int k0 = blockIdx.x * 64, n0 = blockIdx.y * 64;
  int t = threadIdx.x;
  int l16 = t & 15, rg = t >> 4;
#pragma unroll
  for (int i = 0; i < 4; i++) {
    int r = rg + i * 16;
    float4 vv = *(const float4*)(W + (size_t)(k0 + r) * N + n0 + l16 * 4);
    tl[r][l16 * 4 + 0] = vv.x;
    tl[r][l16 * 4 + 1] = vv.y;
    tl[r][l16 * 4 + 2] = vv.z;
    tl[r][l16 * 4 + 3] = vv.w;
  }
  __syncthreads();
#pragma unroll
  for (int i = 0; i < 4; i++) {
    int nrow = rg + i * 16;
    ushort4 o;
    o.x = f2bf(tl[l16 * 4 + 0][nrow]);
    o.y = f2bf(tl[l16 * 4 + 1][nrow]);
    o.z = f2bf(tl[l16 * 4 + 2][nrow]);
    o.w = f2bf(tl[l16 * 4 + 3][nrow]);
    *(ushort4*)(Wt + (size_t)(n0 + nrow) * K + k0 + l16 * 4) = o;
  }
}

// ---------------- bf16 MFMA GEMM (m97 structure): C = A[M,K] @ Bt[N,K]^T + bias ----
// EPI: 0 = bias, fp32 out; 1 = bias + exact gelu, bf16 out
template <int EPI>
__global__ __launch_bounds__(256) void mfma_gemm_kernel(
    const u16* __restrict__ A, const u16* __restrict__ Bt,
    const float* __restrict__ bias, float* __restrict__ Cf,
    u16* __restrict__ Cb, int M, int N, int K) {
  __shared__ u16 As[128 * 32];
  __shared__ u16 Bs[128 * 32];
  int t = threadIdx.x;
  int lane = t & 63;
  int w = t >> 6;
  int m0 = blockIdx.x * 128, n0 = blockIdx.y * 128;
  int wm = (w >> 1) * 64, wn = (w & 1) * 64;

  f32x4 acc[4][4];
#pragma unroll
  for (int i = 0; i < 4; i++)
#pragma unroll
    for (int j = 0; j < 4; j++) acc[i][j] = (f32x4){0.f, 0.f, 0.f, 0.f};

  int rA = lane >> 2;            // row within a 16-row staging chunk
  int kseg = (lane & 3) * 8;     // k element offset within BK=32
  const u16* gA0 = A + (size_t)(m0 + 2 * w * 16 + rA) * K + kseg;
  const u16* gB0 = Bt + (size_t)(n0 + 2 * w * 16 + rA) * K + kseg;
  char* lA0 = (char*)As + (2 * w) * 1024;
  char* lB0 = (char*)Bs + (2 * w) * 1024;

  const u16* fA = As + (wm + (lane & 15)) * 32 + (lane >> 4) * 8;
  const u16* fB = Bs + (wn + (lane & 15)) * 32 + (lane >> 4) * 8;

  for (int k0 = 0; k0 < K; k0 += 32) {
    load_lds16(gA0 + k0, lA0);
    load_lds16(gA0 + (size_t)16 * K + k0, lA0 + 1024);
    load_lds16(gB0 + k0, lB0);
    load_lds16(gB0 + (size_t)16 * K + k0, lB0 + 1024);
    __syncthreads();
    bf16x8 fa[4], fb[4];
#pragma unroll
    for (int i = 0; i < 4; i++) {
      fa[i] = *(const bf16x8*)(fA + i * 16 * 32);
      fb[i] = *(const bf16x8*)(fB + i * 16 * 32);
    }
#pragma unroll
    for (int mi = 0; mi < 4; mi++)
#pragma unroll
      for (int ni = 0; ni < 4; ni++)
        acc[mi][ni] = __builtin_amdgcn_mfma_f32_16x16x32_bf16(
            fa[mi], fb[ni], acc[mi][ni], 0, 0, 0);
    __syncthreads();
  }

  int col0 = n0 + wn + (lane & 15);
  int row0 = m0 + wm + (lane >> 4) * 4;
#pragma unroll
  for (int mi = 0; mi < 4; mi++)
#pragma unroll
    for (int ni = 0; ni < 4; ni++) {
      int ncol = col0 + ni * 16;
      float bv = bias[ncol];
#pragma unroll
      for (int r = 0; r < 4; r++) {
        int mrow = row0 + mi * 16 + r;
        float vv = acc[mi][ni][r] + bv;
        if (EPI == 1) {
          vv = 0.5f * vv * (1.f + erff(vv * 0.70710678118654752f));
          Cb[(size_t)mrow * N + ncol] = f2bf(vv);
        } else {
          Cf[(size_t)mrow * N + ncol] = vv;
        }
      }
    }
}

// ---------------- local (banded) attention, distributed online softmax ----------
// grid = B*H*8*8; block handles (b,h,chunk n, 32-query group); bf16 output
__global__ __launch_bounds__(256) void local_attn_kernel(
    const float* __restrict__ q, const float* __restrict__ k,
    const float* __restrict__ v, const float* __restrict__ amask,
    u16* __restrict__ Ob) {
  int x = blockIdx.x;
  int qg = x & 7;
  int n  = (x >> 3) & 7;
  int hh = (x >> 6) % NHEAD;
  int bb = (x >> 6) / NHEAD;
  int q0 = n * 256 + qg * 32;

  __shared__ float qs[32][68];
  __shared__ float ks[64][68];
  __shared__ float vs[64][68];
  __shared__ float sc[32][68];
  __shared__ float k0s[64], v0s[64];

  int t = threadIdx.x;
  int qi = t >> 3;
  int g  = t & 7;

#pragma unroll
  for (int i = 0; i < 2; i++) {
    int f = t + i * 256;
    int r = f >> 4, seg = f & 15;
    *(float4*)(&qs[r][seg * 4]) = *(const float4*)(
        q + ((size_t)(bb * SSEQ + q0 + r)) * DMODEL + hh * DHEAD + seg * 4);
  }
  if (t < 64) {
    size_t base = ((size_t)(bb * SSEQ)) * DMODEL + hh * DHEAD + t;
    k0s[t] = k[base];
    v0s[t] = v[base];
  }
  float mrun = -INFINITY, lrun = 0.f;
  float o[8];
#pragma unroll
  for (int i = 0; i < 8; i++) o[i] = 0.f;
  __syncthreads();

  for (int tile = 0; tile < 12; tile++) {
    int jp0 = (n - 1) * 256 + tile * 64;
    if (jp0 + 63 < 0 || jp0 >= SSEQ) continue;
    if (jp0 + 63 < q0 - 256 || jp0 > q0 + 31 + 256) continue;

#pragma unroll
    for (int i = 0; i < 4; i++) {
      int f = t + i * 256;
      int r = f >> 4, seg = f & 15;
      int jp = jp0 + r;
      float4 kv = make_float4(0.f, 0.f, 0.f, 0.f);
      float4 vv = make_float4(0.f, 0.f, 0.f, 0.f);
      if (jp >= 0 && jp < SSEQ) {
        size_t base = ((size_t)(bb * SSEQ + jp)) * DMODEL + hh * DHEAD + seg * 4;
        kv = *(const float4*)(k + base);
        vv = *(const float4*)(v + base);
      }
      *(float4*)(&ks[r][seg * 4]) = kv;
      *(float4*)(&vs[r][seg * 4]) = vv;
    }
    __syncthreads();

    // QK^T: thread -> (qi, keys j = jj*8 + g)
    float acc8[8];
#pragma unroll
    for (int jj = 0; jj < 8; jj++) acc8[jj] = 0.f;
#pragma unroll 4
    for (int c4 = 0; c4 < 16; c4++) {
      float4 qv = *(float4*)(&qs[qi][c4 * 4]);
#pragma unroll
      for (int jj = 0; jj < 8; jj++) {
        float4 kv = *(float4*)(&ks[jj * 8 + g][c4 * 4]);
        acc8[jj] = fmaf(qv.x, kv.x, acc8[jj]);
        acc8[jj] = fmaf(qv.y, kv.y, acc8[jj]);
        acc8[jj] = fmaf(qv.z, kv.z, acc8[jj]);
        acc8[jj] = fmaf(qv.w, kv.w, acc8[jj]);
      }
    }
    int qpos = q0 + qi;
    float sreg[8];
    float mx8 = -INFINITY;
#pragma unroll
    for (int jj = 0; jj < 8; jj++) {
      int jp = jp0 + jj * 8 + g;
      int rel = jp - qpos;
      bool ok = (jp >= 0) && (jp < SSEQ) && (jp != 0) && (rel <= 256) && (rel >= -256);
      if (ok) ok = amask[bb * SSEQ + jp] > 0.5f;
      float s = ok ? acc8[jj] * QSCALE : NEGV;
      sreg[jj] = s;
      mx8 = fmaxf(mx8, s);
    }
    // reduce max/sum across the 8 g-lanes sharing this query (lane = (qi&7)*8+g)
#pragma unroll
    for (int mm = 1; mm < 8; mm <<= 1) mx8 = fmaxf(mx8, __shfl_xor(mx8, mm, 64));
    float mnew = fmaxf(mrun, mx8);       // finite: mx8 >= NEGV
    float cr = expf(mrun - mnew);        // first tile: exp(-inf)=0
    float ssum = 0.f;
#pragma unroll
    for (int jj = 0; jj < 8; jj++) {
      float e = expf(sreg[jj] - mnew);
      sc[qi][jj * 8 + g] = e;
      ssum += e;
    }
#pragma unroll
    for (int mm = 1; mm < 8; mm <<= 1) ssum += __shfl_xor(ssum, mm, 64);
    lrun = lrun * cr + ssum;
    mrun = mnew;

    // P@V: thread owns (qi, dims g*8..g*8+7); sc written by same wave
#pragma unroll
    for (int i = 0; i < 8; i++) o[i] *= cr;
#pragma unroll 4
    for (int j = 0; j < 64; j++) {
      float p = sc[qi][j];
      float4 v0 = *(float4*)(&vs[j][g * 8]);
      float4 v1 = *(float4*)(&vs[j][g * 8 + 4]);
      o[0] = fmaf(p, v0.x, o[0]);
      o[1] = fmaf(p, v0.y, o[1]);
      o[2] = fmaf(p, v0.z, o[2]);
      o[3] = fmaf(p, v0.w, o[3]);
      o[4] = fmaf(p, v1.x, o[4]);
      o[5] = fmaf(p, v1.y, o[5]);
      o[6] = fmaf(p, v1.z, o[6]);
      o[7] = fmaf(p, v1.w, o[7]);
    }
    __syncthreads();
  }

  // global token-0 key column (joint softmax, never masked)
  float gs8 = 0.f;
#pragma unroll
  for (int i = 0; i < 8; i++) gs8 = fmaf(qs[qi][g * 8 + i], k0s[g * 8 + i], gs8);
#pragma unroll
  for (int mm = 1; mm < 8; mm <<= 1) gs8 += __shfl_xor(gs8, mm, 64);
  float gsc = gs8 * QSCALE;
  float mnew = fmaxf(mrun, gsc);
  float cr = expf(mrun - mnew);
  float p0 = expf(gsc - mnew);
  float linv = 1.0f / (lrun * cr + p0);
  ushort4 s0, s1;
  s0.x = f2bf((o[0] * cr + p0 * v0s[g * 8 + 0]) * linv);
  s0.y = f2bf((o[1] * cr + p0 * v0s[g * 8 + 1]) * linv);
  s0.z = f2bf((o[2] * cr + p0 * v0s[g * 8 + 2]) * linv);
  s0.w = f2bf((o[3] * cr + p0 * v0s[g * 8 + 3]) * linv);
  s1.x = f2bf((o[4] * cr + p0 * v0s[g * 8 + 4]) * linv);
  s1.y = f2bf((o[5] * cr + p0 * v0s[g * 8 + 5]) * linv);
  s1.z = f2bf((o[6] * cr + p0 * v0s[g * 8 + 6]) * linv);
  s1.w = f2bf((o[7] * cr + p0 * v0s[g * 8 + 7]) * linv);
  size_t base = ((size_t)(bb * SSEQ + q0 + qi)) * DMODEL + hh * DHEAD + g * 8;
  *(ushort4*)(Ob + base)     = s0;
  *(ushort4*)(Ob + base + 4) = s1;
}

// ---------------- global token-0 query attention: grid = B*H, bf16 out --------
__global__ __launch_bounds__(256) void global_attn_kernel(
    const float* __restrict__ qg, const float* __restrict__ kg,
    const float* __restrict__ vg, const float* __restrict__ amask,
    u16* __restrict__ Ob) {
  int bb = blockIdx.x / NHEAD;
  int hh = blockIdx.x % NHEAD;
  __shared__ float p[SSEQ];
  __shared__ float qv[64];
  __shared__ float red[256];
  __shared__ float part[4][64];
  int t = threadIdx.x;
  if (t < 64) qv[t] = qg[(bb * NHEAD + hh) * 64 + t];
  __syncthreads();
  float mx = -INFINITY;
#pragma unroll
  for (int i = 0; i < 8; i++) {
    int s = t + i * 256;
    const float* kp = kg + ((size_t)(bb * SSEQ + s)) * DMODEL + hh * DHEAD;
    float acc = 0.f;
    for (int d = 0; d < 64; d += 4) {
      float4 kv = *(const float4*)(kp + d);
      acc = fmaf(qv[d], kv.x, acc);
      acc = fmaf(qv[d + 1], kv.y, acc);
      acc = fmaf(qv[d + 2], kv.z, acc);
      acc = fmaf(qv[d + 3], kv.w, acc);
    }
    if (!(amask[bb * SSEQ + s] > 0.5f)) acc = NEGV;
    p[s] = acc;
    mx = fmaxf(mx, acc);
  }
  red[t] = mx;
  __syncthreads();
  for (int sft = 128; sft > 0; sft >>= 1) {
    if (t < sft) red[t] = fmaxf(red[t], red[t + sft]);
    __syncthreads();
  }
  mx = red[0];
  __syncthreads();
  float lsum = 0.f;
#pragma unroll
  for (int i = 0; i < 8; i++) {
    int s = t + i * 256;
    float e = expf(p[s] - mx);
    p[s] = e;
    lsum += e;
  }
  float l = block_sum_256(lsum, red);
  int d = t & 63, stripe = t >> 6;
  float acc = 0.f;
  for (int s = stripe * 512; s < stripe * 512 + 512; s++) {
    acc = fmaf(p[s], vg[((size_t)(bb * SSEQ + s)) * DMODEL + hh * DHEAD + d], acc);
  }
  part[stripe][d] = acc;
  __syncthreads();
  if (t < 64) {
    float sum = part[0][t] + part[1][t] + part[2][t] + part[3][t];
    Ob[((size_t)(bb * SSEQ)) * DMODEL + hh * DHEAD + t] = f2bf(sum / l);
  }
}

// ---------------- tiny row-vector x matrix (fp32) ----------------
__global__ __launch_bounds__(256) void rowvec_mat_kernel(
    const float* __restrict__ x, size_t xstride, const float* __restrict__ Wt,
    const float* __restrict__ bias, float* __restrict__ y, int K, int N,
    float scl, int act) {
  int ncg = N >> 8;
  int bb = blockIdx.x / ncg;
  int cg = blockIdx.x % ncg;
  int j = cg * 256 + threadIdx.x;
  const float* xr = x + (size_t)bb * xstride;
  float acc = bias[j];
  for (int kk = 0; kk < K; kk++) acc = fmaf(xr[kk], Wt[(size_t)kk * N + j], acc);
  acc *= scl;
  if (act == 1) acc = tanhf(acc);
  y[(size_t)bb * N + j] = acc;
}

// ---------------- final head ----------------
__global__ __launch_bounds__(256) void head_kernel(
    const float* __restrict__ pooled, const float* __restrict__ clsW,
    const float* __restrict__ clsb, const float* __restrict__ mcW,
    const float* __restrict__ mcb, float* __restrict__ out) {
  __shared__ float lg[8];
  __shared__ float o16[16];
  int t = threadIdx.x;
  if (t < 8) {
    int bb = t >> 1, cc2 = t & 1;
    float acc = clsb[cc2];
    for (int kk = 0; kk < DMODEL; kk++)
      acc = fmaf(pooled[bb * DMODEL + kk], clsW[kk * 2 + cc2], acc);
    lg[t] = acc;
  }
  __syncthreads();
  if (t < 16) {
    float acc = mcb[t];
    for (int i = 0; i < 8; i++) acc = fmaf(lg[i], mcW[i * 16 + t], acc);
    o16[t] = acc;
  }
  __syncthreads();
  if (t == 0) {
    float mx = o16[0];
    for (int i = 1; i < 16; i++) mx = fmaxf(mx, o16[i]);
    float sum = 0.f;
    float e[16];
    for (int i = 0; i < 16; i++) { e[i] = expf(o16[i] - mx); sum += e[i]; }
    for (int i = 0; i < 16; i++) out[i] = e[i] / sum;
  }
}

// ---------------- host launcher ----------------
extern "C" void kernel_launch(void* const* d_in, const int* in_sizes, int n_in,
                              void* d_out, int out_size, void* d_ws, size_t ws_size,
                              hipStream_t stream) {
  (void)in_sizes; (void)n_in; (void)out_size; (void)ws_size;
  const int*   ids      = (const int*)d_in[0];
  const float* amask    = (const float*)d_in[1];
  const float* emb_word = (const float*)d_in[2];
  const float* emb_pos  = (const float*)d_in[3];
  const float* ln_emb_s = (const float*)d_in[4];
  const float* ln_emb_b = (const float*)d_in[5];
  const float* Wq  = (const float*)d_in[6];
  const float* Wk  = (const float*)d_in[7];
  const float* Wv  = (const float*)d_in[8];
  const float* Wqg = (const float*)d_in[9];
  const float* Wkg = (const float*)d_in[10];
  const float* Wvg = (const float*)d_in[11];
  const float* Wo  = (const float*)d_in[12];
  const float* bq  = (const float*)d_in[13];
  const float* bk  = (const float*)d_in[14];
  const float* bv  = (const float*)d_in[15];
  const float* bqg = (const float*)d_in[16];
  const float* bkg = (const float*)d_in[17];
  const float* bvg = (const float*)d_in[18];
  const float* bo  = (const float*)d_in[19];
  const float* ln1_s = (const float*)d_in[20];
  const float* ln1_b = (const float*)d_in[21];
  const float* Wi  = (const float*)d_in[22];
  const float* bi  = (const float*)d_in[23];
  const float* Wf  = (const float*)d_in[24];
  const float* bf_ = (const float*)d_in[25];
  const float* ln2_s = (const float*)d_in[26];
  const float* ln2_b = (const float*)d_in[27];
  const float* pooler_W = (const float*)d_in[28];
  const float* pooler_b = (const float*)d_in[29];
  const float* cls_W = (const float*)d_in[30];
  const float* cls_b = (const float*)d_in[31];
  const float* mc_W  = (const float*)d_in[32];
  const float* mc_b  = (const float*)d_in[33];
  float* out = (float*)d_out;

  float* ws = (float*)d_ws;
  const size_t NT = (size_t)BBATCH * SSEQ;   // 8192 tokens
  const size_t TD = NT * DMODEL;             // 6.29M floats per fp32 panel
  float* h    = ws;                          // [NT, D] fp32
  float* Pa   = ws + TD;                     // fp32 panel (q / kg)
  float* Pb   = ws + 2 * TD;                 // fp32 panel (k / vg)
  float* Pc   = ws + 3 * TD;                 // fp32 panel (v / proj-out)
  u16*   hb   = (u16*)(ws + 4 * TD);         // [NT, D] bf16
  u16*   attb = (u16*)(ws + 4 * TD) + TD;    // [NT, D] bf16 attention out
  u16*   midb = (u16*)(ws + 5 * TD);         // [NT, DFF] bf16 (spans 2 TD-floats)
  u16*   wt   = (u16*)(ws + 7 * TD);         // per-layer bf16 weights (16.5 MB)
  float* qgb    = ws + 8 * TD;               // [B, D]
  float* pooled = qgb + BBATCH * DMODEL;     // [B, D]

  const size_t WDD = (size_t)DMODEL * DMODEL;     // 589824
  u16* wqT  = wt;
  u16* wkT  = wt + WDD;
  u16* wvT  = wt + 2 * WDD;
  u16* wkgT = wt + 3 * WDD;
  u16* wvgT = wt + 4 * WDD;
  u16* woT  = wt + 5 * WDD;
  u16* wiT  = wt + 6 * WDD;                        // [DFF, D]
  u16* wfT  = wiT + (size_t)DMODEL * DFFN;         // [D, DFF]

  embed_ln_kernel<<<(int)NT, 256, 0, stream>>>(ids, emb_word, emb_pos,
                                               ln_emb_s, ln_emb_b, h, hb);

  dim3 gDD(NT / 128, DMODEL / 128);   // (64, 6)
  dim3 gF1(NT / 128, DFFN / 128);     // (64, 24)
  dim3 cDD(DMODEL / 64, DMODEL / 64); // (12, 12)
  dim3 cWi(DMODEL / 64, DFFN / 64);   // (12, 48)
  dim3 cWf(DFFN / 64, DMODEL / 64);   // (48, 12)

  for (int l = 0; l < NLAYER; l++) {
    const size_t wd = (size_t)l * WDD;
    // weight convert+transpose (bf16 [N,K])
    convt_kernel<<<cDD, 256, 0, stream>>>(Wq  + wd, wqT,  DMODEL, DMODEL);
    convt_kernel<<<cDD, 256, 0, stream>>>(Wk  + wd, wkT,  DMODEL, DMODEL);
    convt_kernel<<<cDD, 256, 0, stream>>>(Wv  + wd, wvT,  DMODEL, DMODEL);
    convt_kernel<<<cDD, 256, 0, stream>>>(Wkg + wd, wkgT, DMODEL, DMODEL);
    convt_kernel<<<cDD, 256, 0, stream>>>(Wvg + wd, wvgT, DMODEL, DMODEL);
    convt_kernel<<<cDD, 256, 0, stream>>>(Wo  + wd, woT,  DMODEL, DMODEL);
    convt_kernel<<<cWi, 256, 0, stream>>>(Wi + (size_t)l * DMODEL * DFFN, wiT, DMODEL, DFFN);
    convt_kernel<<<cWf, 256, 0, stream>>>(Wf + (size_t)l * DMODEL * DFFN, wfT, DFFN, DMODEL);

    // q,k,v projections (bf16 MFMA, fp32 out)
    mfma_gemm_kernel<0><<<gDD, 256, 0, stream>>>(hb, wqT, bq + l * DMODEL, Pa, (u16*)nullptr, (int)NT, DMODEL, DMODEL);
    mfma_gemm_kernel<0><<<gDD, 256, 0, stream>>>(hb, wkT, bk + l * DMODEL, Pb, (u16*)nullptr, (int)NT, DMODEL, DMODEL);
    mfma_gemm_kernel<0><<<gDD, 256, 0, stream>>>(hb, wvT, bv + l * DMODEL, Pc, (u16*)nullptr, (int)NT, DMODEL, DMODEL);
    // banded local attention -> bf16 panel
    local_attn_kernel<<<BBATCH * NHEAD * 8 * 8, 256, 0, stream>>>(Pa, Pb, Pc, amask, attb);
    // global k/v projections
    mfma_gemm_kernel<0><<<gDD, 256, 0, stream>>>(hb, wkgT, bkg + l * DMODEL, Pa, (u16*)nullptr, (int)NT, DMODEL, DMODEL);
    mfma_gemm_kernel<0><<<gDD, 256, 0, stream>>>(hb, wvgT, bvg + l * DMODEL, Pb, (u16*)nullptr, (int)NT, DMODEL, DMODEL);
    rowvec_mat_kernel<<<BBATCH * 3, 256, 0, stream>>>(h, (size_t)SSEQ * DMODEL,
        Wqg + wd, bqg + l * DMODEL, qgb, DMODEL, DMODEL, QSCALE, 0);
    global_attn_kernel<<<BBATCH * NHEAD, 256, 0, stream>>>(qgb, Pa, Pb, amask, attb);
    // output projection + residual LN
    mfma_gemm_kernel<0><<<gDD, 256, 0, stream>>>(attb, woT, bo + l * DMODEL, Pc, (u16*)nullptr, (int)NT, DMODEL, DMODEL);
    add_ln_kernel<<<(int)NT, 256, 0, stream>>>(h, Pc, ln1_s + l * DMODEL, ln1_b + l * DMODEL, hb);
    // FFN
    mfma_gemm_kernel<1><<<gF1, 256, 0, stream>>>(hb, wiT, bi + l * DFFN, (float*)nullptr, midb, (int)NT, DFFN, DMODEL);
    mfma_gemm_kernel<0><<<gDD, 256, 0, stream>>>(midb, wfT, bf_ + l * DMODEL, Pc, (u16*)nullptr, (int)NT, DMODEL, DFFN);
    add_ln_kernel<<<(int)NT, 256, 0, stream>>>(h, Pc, ln2_s + l * DMODEL, ln2_b + l * DMODEL, hb);
  }

  rowvec_mat_kernel<<<BBATCH * 3, 256, 0, stream>>>(h, (size_t)SSEQ * DMODEL,
      pooler_W, pooler_b, pooled, DMODEL, DMODEL, 1.0f, 1);
  head_kernel<<<1, 256, 0, stream>>>(pooled, cls_W, cls_b, mc_W, mc_b, out);
}

// Round 3
// 12504.382 us; speedup vs baseline: 4.3823x; 1.0775x over previous
//
#include <hip/hip_runtime.h>
#include <hip/hip_bf16.h>
#include <math.h>

#define BBATCH 4
#define SSEQ   2048
#define DMODEL 768
#define NHEAD  12
#define DHEAD  64
#define DFFN   3072
#define NLAYER 12
#define NEGV   (-1e9f)
#define QSCALE 0.125f
#define NQKV   3840   // 5*768: q|k|v|kg|vg interleaved per token

typedef unsigned short u16;
typedef unsigned int u32;
typedef __attribute__((ext_vector_type(8))) short bf16x8;
typedef __attribute__((ext_vector_type(4))) float f32x4;

__device__ __forceinline__ u16 f2bf(float x) {
  __hip_bfloat16 h = __float2bfloat16(x);
  union { __hip_bfloat16 h; u16 u; } c;
  c.h = h;
  return c.u;
}

__device__ __forceinline__ void unpack8(uint4 r, float* o) {
  o[0] = __uint_as_float(r.x << 16); o[1] = __uint_as_float(r.x & 0xffff0000u);
  o[2] = __uint_as_float(r.y << 16); o[3] = __uint_as_float(r.y & 0xffff0000u);
  o[4] = __uint_as_float(r.z << 16); o[5] = __uint_as_float(r.z & 0xffff0000u);
  o[6] = __uint_as_float(r.w << 16); o[7] = __uint_as_float(r.w & 0xffff0000u);
}

__device__ __forceinline__ void load_lds16(const void* g, void* l) {
  __builtin_amdgcn_global_load_lds(
      (const __attribute__((address_space(1))) unsigned int*)g,
      (__attribute__((address_space(3))) unsigned int*)l, 16, 0, 0);
}

// ---------------- block reduction helper (256 threads) ----------------
__device__ __forceinline__ float block_sum_256(float v, float* red) {
  int t = threadIdx.x;
  red[t] = v;
  __syncthreads();
#pragma unroll
  for (int s = 128; s > 0; s >>= 1) {
    if (t < s) red[t] += red[t + s];
    __syncthreads();
  }
  float r = red[0];
  __syncthreads();
  return r;
}

// ---------------- embeddings + LN (dual write fp32 + bf16) ----------------
__global__ __launch_bounds__(256) void embed_ln_kernel(
    const int* __restrict__ ids, const float* __restrict__ ew,
    const float* __restrict__ ep, const float* __restrict__ lns,
    const float* __restrict__ lnb, float* __restrict__ h,
    u16* __restrict__ hb) {
  __shared__ float red[256];
  int tok = blockIdx.x;
  int s = tok % SSEQ;
  int id = ids[tok];
  const float* wp = ew + (size_t)id * DMODEL;
  const float* pp = ep + (size_t)s * DMODEL;
  float vals[3];
  float sum = 0.f;
#pragma unroll
  for (int i = 0; i < 3; i++) {
    int d = threadIdx.x + i * 256;
    vals[i] = wp[d] + pp[d];
    sum += vals[i];
  }
  float mean = block_sum_256(sum, red) * (1.0f / DMODEL);
  float vsum = 0.f;
#pragma unroll
  for (int i = 0; i < 3; i++) { float df = vals[i] - mean; vsum += df * df; }
  float var = block_sum_256(vsum, red) * (1.0f / DMODEL);
  float inv = rsqrtf(var + 1e-5f);
#pragma unroll
  for (int i = 0; i < 3; i++) {
    int d = threadIdx.x + i * 256;
    float o = (vals[i] - mean) * inv * lns[d] + lnb[d];
    h[(size_t)tok * DMODEL + d] = o;
    hb[(size_t)tok * DMODEL + d] = f2bf(o);
  }
}

// ---------------- h = LN(h + delta), dual write ----------------
__global__ __launch_bounds__(256) void add_ln_kernel(
    float* __restrict__ h, const float* __restrict__ delta,
    const float* __restrict__ lns, const float* __restrict__ lnb,
    u16* __restrict__ hb) {
  __shared__ float red[256];
  size_t base = (size_t)blockIdx.x * DMODEL;
  float vals[3];
  float sum = 0.f;
#pragma unroll
  for (int i = 0; i < 3; i++) {
    int d = threadIdx.x + i * 256;
    vals[i] = h[base + d] + delta[base + d];
    sum += vals[i];
  }
  float mean = block_sum_256(sum, red) * (1.0f / DMODEL);
  float vsum = 0.f;
#pragma unroll
  for (int i = 0; i < 3; i++) { float df = vals[i] - mean; vsum += df * df; }
  float var = block_sum_256(vsum, red) * (1.0f / DMODEL);
  float inv = rsqrtf(var + 1e-5f);
#pragma unroll
  for (int i = 0; i < 3; i++) {
    int d = threadIdx.x + i * 256;
    float o = (vals[i] - mean) * inv * lns[d] + lnb[d];
    h[base + d] = o;
    hb[base + d] = f2bf(o);
  }
}

// ---------------- transpose+convert 64x64 tile body ----------------
__device__ __forceinline__ void convt_tile(const float* __restrict__ W,
                                           u16* __restrict__ Wt, int K, int N) {
  __shared__ float tl[64][65];
  int k0 = blockIdx.x * 64, n0 = blockIdx.y * 64;
  int t = threadIdx.x;
  int l16 = t & 15, rg = t >> 4;
#pragma unroll
  for (int i = 0; i < 4; i++) {
    int r = rg + i * 16;
    float4 vv = *(const float4*)(W + (size_t)(k0 + r) * N + n0 + l16 * 4);
    tl[r][l16 * 4 + 0] = vv.x;
    tl[r][l16 * 4 + 1] = vv.y;
    tl[r][l16 * 4 + 2] = vv.z;
    tl[r][l16 * 4 + 3] = vv.w;
  }
  __syncthreads();
#pragma unroll
  for (int i = 0; i < 4; i++) {
    int nrow = rg + i * 16;
    ushort4 o;
    o.x = f2bf(tl[l16 * 4 + 0][nrow]);
    o.y = f2bf(tl[l16 * 4 + 1][nrow]);
    o.z = f2bf(tl[l16 * 4 + 2][nrow]);
    o.w = f2bf(tl[l16 * 4 + 3][nrow]);
    *(ushort4*)(Wt + (size_t)(n0 + nrow) * K + k0 + l16 * 4) = o;
  }
}

// generic convt (Wi / Wf)
__global__ __launch_bounds__(256) void convt_kernel(
    const float* __restrict__ W, u16* __restrict__ Wt, int K, int N) {
  convt_tile(W, Wt, K, N);
}

// fused convt of six DxD matrices (q,k,v,kg,vg,wo) via blockIdx.z
__global__ __launch_bounds__(256) void convt6_kernel(
    const float* __restrict__ W0, const float* __restrict__ W1,
    const float* __restrict__ W2, const float* __restrict__ W3,
    const float* __restrict__ W4, const float* __restrict__ W5,
    u16* __restrict__ out) {
  int z = blockIdx.z;
  const float* W = (z == 0) ? W0 : (z == 1) ? W1 : (z == 2) ? W2
                 : (z == 3) ? W3 : (z == 4) ? W4 : W5;
  convt_tile(W, out + (size_t)z * DMODEL * DMODEL, DMODEL, DMODEL);
}

// concat per-layer biases bq|bk|bv|bkg|bvg -> fb[L][NQKV] (run once)
__global__ __launch_bounds__(256) void bias_cat_kernel(
    const float* __restrict__ bq, const float* __restrict__ bk,
    const float* __restrict__ bv, const float* __restrict__ bkg,
    const float* __restrict__ bvg, float* __restrict__ fb) {
  int idx = blockIdx.x * 256 + threadIdx.x;
  if (idx >= NLAYER * NQKV) return;
  int l = idx / NQKV, j = idx % NQKV;
  float v;
  if (j < 768)       v = bq[l * DMODEL + j];
  else if (j < 1536) v = bk[l * DMODEL + j - 768];
  else if (j < 2304) v = bv[l * DMODEL + j - 1536];
  else if (j < 3072) v = bkg[l * DMODEL + j - 2304];
  else               v = bvg[l * DMODEL + j - 3072];
  fb[idx] = v;
}

// ---------------- bf16 MFMA GEMM (m97 structure): C = A[M,K] @ Bt[N,K]^T + bias ----
// EPI: 0 = bias -> fp32 out; 1 = bias+gelu -> bf16 out; 2 = bias -> bf16 out
template <int EPI>
__global__ __launch_bounds__(256) void mfma_gemm_kernel(
    const u16* __restrict__ A, const u16* __restrict__ Bt,
    const float* __restrict__ bias, float* __restrict__ Cf,
    u16* __restrict__ Cb, int M, int N, int K) {
  __shared__ u16 As[128 * 32];
  __shared__ u16 Bs[128 * 32];
  int t = threadIdx.x;
  int lane = t & 63;
  int w = t >> 6;
  int m0 = blockIdx.x * 128, n0 = blockIdx.y * 128;
  int wm = (w >> 1) * 64, wn = (w & 1) * 64;

  f32x4 acc[4][4];
#pragma unroll
  for (int i = 0; i < 4; i++)
#pragma unroll
    for (int j = 0; j < 4; j++) acc[i][j] = (f32x4){0.f, 0.f, 0.f, 0.f};

  int rA = lane >> 2;
  int kseg = (lane & 3) * 8;
  const u16* gA0 = A + (size_t)(m0 + 2 * w * 16 + rA) * K + kseg;
  const u16* gB0 = Bt + (size_t)(n0 + 2 * w * 16 + rA) * K + kseg;
  char* lA0 = (char*)As + (2 * w) * 1024;
  char* lB0 = (char*)Bs + (2 * w) * 1024;

  const u16* fA = As + (wm + (lane & 15)) * 32 + (lane >> 4) * 8;
  const u16* fB = Bs + (wn + (lane & 15)) * 32 + (lane >> 4) * 8;

  for (int k0 = 0; k0 < K; k0 += 32) {
    load_lds16(gA0 + k0, lA0);
    load_lds16(gA0 + (size_t)16 * K + k0, lA0 + 1024);
    load_lds16(gB0 + k0, lB0);
    load_lds16(gB0 + (size_t)16 * K + k0, lB0 + 1024);
    __syncthreads();
    bf16x8 fa[4], fb[4];
#pragma unroll
    for (int i = 0; i < 4; i++) {
      fa[i] = *(const bf16x8*)(fA + i * 16 * 32);
      fb[i] = *(const bf16x8*)(fB + i * 16 * 32);
    }
#pragma unroll
    for (int mi = 0; mi < 4; mi++)
#pragma unroll
      for (int ni = 0; ni < 4; ni++)
        acc[mi][ni] = __builtin_amdgcn_mfma_f32_16x16x32_bf16(
            fa[mi], fb[ni], acc[mi][ni], 0, 0, 0);
    __syncthreads();
  }

  int col0 = n0 + wn + (lane & 15);
  int row0 = m0 + wm + (lane >> 4) * 4;
#pragma unroll
  for (int mi = 0; mi < 4; mi++)
#pragma unroll
    for (int ni = 0; ni < 4; ni++) {
      int ncol = col0 + ni * 16;
      float bv = bias[ncol];
#pragma unroll
      for (int r = 0; r < 4; r++) {
        int mrow = row0 + mi * 16 + r;
        float vv = acc[mi][ni][r] + bv;
        if (EPI == 0) {
          Cf[(size_t)mrow * N + ncol] = vv;
        } else if (EPI == 1) {
          vv = 0.5f * vv * (1.f + erff(vv * 0.70710678118654752f));
          Cb[(size_t)mrow * N + ncol] = f2bf(vv);
        } else {
          Cb[(size_t)mrow * N + ncol] = f2bf(vv);
        }
      }
    }
}

// ---------------- local (banded) attention, bf16 in, distributed softmax -------
// qkv: [NT, NQKV] bf16 panel (q|k|v|kg|vg). grid = B*H*8*8.
__global__ __launch_bounds__(256) void local_attn_kernel(
    const u16* __restrict__ qkv, const float* __restrict__ amask,
    u16* __restrict__ Ob) {
  int x = blockIdx.x;
  int qg = x & 7;
  int n  = (x >> 3) & 7;
  int hh = (x >> 6) % NHEAD;
  int bb = (x >> 6) / NHEAD;
  int q0 = n * 256 + qg * 32;

  __shared__ float qs[32][68];
  __shared__ float ks[64][68];
  __shared__ float vs[64][68];
  __shared__ float sc[32][68];
  __shared__ float sm[64];
  __shared__ float k0s[64], v0s[64];

  int t = threadIdx.x;
  int qi = t >> 3;
  int g  = t & 7;

  // stage 32 query rows (bf16 -> fp32)
  {
    int r = t >> 3, seg = t & 7;
    uint4 raw = *(const uint4*)(qkv + ((size_t)(bb * SSEQ + q0 + r)) * NQKV + hh * DHEAD + seg * 8);
    float f8[8];
    unpack8(raw, f8);
    *(float4*)(&qs[r][seg * 8])     = *(float4*)(f8);
    *(float4*)(&qs[r][seg * 8 + 4]) = *(float4*)(f8 + 4);
  }
  // token-0 key/value (global column)
  if (t < 16) {
    int seg = t & 7;
    int off = (t < 8) ? 768 : 1536;
    uint4 raw = *(const uint4*)(qkv + ((size_t)bb * SSEQ) * NQKV + off + hh * DHEAD + seg * 8);
    float f8[8];
    unpack8(raw, f8);
    float* dst = (t < 8) ? k0s : v0s;
#pragma unroll
    for (int i = 0; i < 8; i++) dst[seg * 8 + i] = f8[i];
  }
  float mrun = -INFINITY, lrun = 0.f;
  float o[8];
#pragma unroll
  for (int i = 0; i < 8; i++) o[i] = 0.f;
  __syncthreads();

  for (int tile = 0; tile < 12; tile++) {
    int jp0 = (n - 1) * 256 + tile * 64;
    if (jp0 + 63 < 0 || jp0 >= SSEQ) continue;
    if (jp0 + 63 < q0 - 256 || jp0 > q0 + 31 + 256) continue;

    // stage k/v tile (bf16 -> fp32), 64 keys x 64 dims each
#pragma unroll
    for (int i = 0; i < 2; i++) {
      int f = t + i * 256;
      int r = f >> 3, seg = f & 7;
      int jp = jp0 + r;
      float fk[8] = {0, 0, 0, 0, 0, 0, 0, 0};
      float fv[8] = {0, 0, 0, 0, 0, 0, 0, 0};
      if (jp >= 0 && jp < SSEQ) {
        size_t base = ((size_t)(bb * SSEQ + jp)) * NQKV + hh * DHEAD + seg * 8;
        unpack8(*(const uint4*)(qkv + base + 768), fk);
        unpack8(*(const uint4*)(qkv + base + 1536), fv);
      }
      *(float4*)(&ks[r][seg * 8])     = *(float4*)(fk);
      *(float4*)(&ks[r][seg * 8 + 4]) = *(float4*)(fk + 4);
      *(float4*)(&vs[r][seg * 8])     = *(float4*)(fv);
      *(float4*)(&vs[r][seg * 8 + 4]) = *(float4*)(fv + 4);
    }
    if (t < 64) {
      int jp = jp0 + t;
      sm[t] = (jp >= 0 && jp < SSEQ) ? amask[bb * SSEQ + jp] : 0.f;
    }
    __syncthreads();

    // QK^T: thread -> (qi, keys j = jj*8 + g)
    float acc8[8];
#pragma unroll
    for (int jj = 0; jj < 8; jj++) acc8[jj] = 0.f;
#pragma unroll 4
    for (int c4 = 0; c4 < 16; c4++) {
      float4 qv = *(float4*)(&qs[qi][c4 * 4]);
#pragma unroll
      for (int jj = 0; jj < 8; jj++) {
        float4 kv = *(float4*)(&ks[jj * 8 + g][c4 * 4]);
        acc8[jj] = fmaf(qv.x, kv.x, acc8[jj]);
        acc8[jj] = fmaf(qv.y, kv.y, acc8[jj]);
        acc8[jj] = fmaf(qv.z, kv.z, acc8[jj]);
        acc8[jj] = fmaf(qv.w, kv.w, acc8[jj]);
      }
    }
    int qpos = q0 + qi;
    float sreg[8];
    float mx8 = -INFINITY;
#pragma unroll
    for (int jj = 0; jj < 8; jj++) {
      int j = jj * 8 + g;
      int jp = jp0 + j;
      int rel = jp - qpos;
      bool ok = (jp != 0) && (rel <= 256) && (rel >= -256) && (sm[j] > 0.5f);
      float s = ok ? acc8[jj] * QSCALE : NEGV;
      sreg[jj] = s;
      mx8 = fmaxf(mx8, s);
    }
#pragma unroll
    for (int mm = 1; mm < 8; mm <<= 1) mx8 = fmaxf(mx8, __shfl_xor(mx8, mm, 64));
    float mnew = fmaxf(mrun, mx8);
    float cr = expf(mrun - mnew);
    float ssum = 0.f;
#pragma unroll
    for (int jj = 0; jj < 8; jj++) {
      float e = expf(sreg[jj] - mnew);
      sc[qi][jj * 8 + g] = e;
      ssum += e;
    }
#pragma unroll
    for (int mm = 1; mm < 8; mm <<= 1) ssum += __shfl_xor(ssum, mm, 64);
    lrun = lrun * cr + ssum;
    mrun = mnew;

    // P@V: thread owns (qi, dims g*8..g*8+7)
#pragma unroll
    for (int i = 0; i < 8; i++) o[i] *= cr;
#pragma unroll 4
    for (int j = 0; j < 64; j++) {
      float p = sc[qi][j];
      float4 v0 = *(float4*)(&vs[j][g * 8]);
      float4 v1 = *(float4*)(&vs[j][g * 8 + 4]);
      o[0] = fmaf(p, v0.x, o[0]);
      o[1] = fmaf(p, v0.y, o[1]);
      o[2] = fmaf(p, v0.z, o[2]);
      o[3] = fmaf(p, v0.w, o[3]);
      o[4] = fmaf(p, v1.x, o[4]);
      o[5] = fmaf(p, v1.y, o[5]);
      o[6] = fmaf(p, v1.z, o[6]);
      o[7] = fmaf(p, v1.w, o[7]);
    }
    __syncthreads();
  }

  // global token-0 key column (joint softmax, never masked)
  float gs8 = 0.f;
#pragma unroll
  for (int i = 0; i < 8; i++) gs8 = fmaf(qs[qi][g * 8 + i], k0s[g * 8 + i], gs8);
#pragma unroll
  for (int mm = 1; mm < 8; mm <<= 1) gs8 += __shfl_xor(gs8, mm, 64);
  float gsc = gs8 * QSCALE;
  float mnew = fmaxf(mrun, gsc);
  float cr = expf(mrun - mnew);
  float p0 = expf(gsc - mnew);
  float linv = 1.0f / (lrun * cr + p0);
  ushort4 s0, s1;
  s0.x = f2bf((o[0] * cr + p0 * v0s[g * 8 + 0]) * linv);
  s0.y = f2bf((o[1] * cr + p0 * v0s[g * 8 + 1]) * linv);
  s0.z = f2bf((o[2] * cr + p0 * v0s[g * 8 + 2]) * linv);
  s0.w = f2bf((o[3] * cr + p0 * v0s[g * 8 + 3]) * linv);
  s1.x = f2bf((o[4] * cr + p0 * v0s[g * 8 + 4]) * linv);
  s1.y = f2bf((o[5] * cr + p0 * v0s[g * 8 + 5]) * linv);
  s1.z = f2bf((o[6] * cr + p0 * v0s[g * 8 + 6]) * linv);
  s1.w = f2bf((o[7] * cr + p0 * v0s[g * 8 + 7]) * linv);
  size_t base = ((size_t)(bb * SSEQ + q0 + qi)) * DMODEL + hh * DHEAD + g * 8;
  *(ushort4*)(Ob + base)     = s0;
  *(ushort4*)(Ob + base + 4) = s1;
}

// ---------------- global token-0 query attention (bf16 kg/vg): grid = B*H ------
__global__ __launch_bounds__(256) void global_attn_kernel(
    const float* __restrict__ qg, const u16* __restrict__ qkv,
    const float* __restrict__ amask, u16* __restrict__ Ob) {
  int bb = blockIdx.x / NHEAD;
  int hh = blockIdx.x % NHEAD;
  __shared__ float p[SSEQ];
  __shared__ float qv[64];
  __shared__ float red[256];
  __shared__ float part[4][64];
  int t = threadIdx.x;
  if (t < 64) qv[t] = qg[(bb * NHEAD + hh) * 64 + t];
  __syncthreads();
  float mx = -INFINITY;
#pragma unroll
  for (int i = 0; i < 8; i++) {
    int s = t + i * 256;
    const u16* kp = qkv + ((size_t)(bb * SSEQ + s)) * NQKV + 2304 + hh * DHEAD;
    float acc = 0.f;
#pragma unroll
    for (int d8 = 0; d8 < 8; d8++) {
      float f8[8];
      unpack8(*(const uint4*)(kp + d8 * 8), f8);
#pragma unroll
      for (int u = 0; u < 8; u++) acc = fmaf(qv[d8 * 8 + u], f8[u], acc);
    }
    if (!(amask[bb * SSEQ + s] > 0.5f)) acc = NEGV;
    p[s] = acc;
    mx = fmaxf(mx, acc);
  }
  red[t] = mx;
  __syncthreads();
  for (int sft = 128; sft > 0; sft >>= 1) {
    if (t < sft) red[t] = fmaxf(red[t], red[t + sft]);
    __syncthreads();
  }
  mx = red[0];
  __syncthreads();
  float lsum = 0.f;
#pragma unroll
  for (int i = 0; i < 8; i++) {
    int s = t + i * 256;
    float e = expf(p[s] - mx);
    p[s] = e;
    lsum += e;
  }
  float l = block_sum_256(lsum, red);
  int d = t & 63, stripe = t >> 6;
  float acc = 0.f;
  for (int s = stripe * 512; s < stripe * 512 + 512; s++) {
    u16 vv = qkv[((size_t)(bb * SSEQ + s)) * NQKV + 3072 + hh * DHEAD + d];
    acc = fmaf(p[s], __uint_as_float(((u32)vv) << 16), acc);
  }
  part[stripe][d] = acc;
  __syncthreads();
  if (t < 64) {
    float sum = part[0][t] + part[1][t] + part[2][t] + part[3][t];
    Ob[((size_t)(bb * SSEQ)) * DMODEL + hh * DHEAD + t] = f2bf(sum / l);
  }
}

// ---------------- tiny row-vector x matrix (fp32) ----------------
__global__ __launch_bounds__(256) void rowvec_mat_kernel(
    const float* __restrict__ x, size_t xstride, const float* __restrict__ Wt,
    const float* __restrict__ bias, float* __restrict__ y, int K, int N,
    float scl, int act) {
  int ncg = N >> 8;
  int bb = blockIdx.x / ncg;
  int cg = blockIdx.x % ncg;
  int j = cg * 256 + threadIdx.x;
  const float* xr = x + (size_t)bb * xstride;
  float acc = bias[j];
  for (int kk = 0; kk < K; kk++) acc = fmaf(xr[kk], Wt[(size_t)kk * N + j], acc);
  acc *= scl;
  if (act == 1) acc = tanhf(acc);
  y[(size_t)bb * N + j] = acc;
}

// ---------------- final head ----------------
__global__ __launch_bounds__(256) void head_kernel(
    const float* __restrict__ pooled, const float* __restrict__ clsW,
    const float* __restrict__ clsb, const float* __restrict__ mcW,
    const float* __restrict__ mcb, float* __restrict__ out) {
  __shared__ float lg[8];
  __shared__ float o16[16];
  int t = threadIdx.x;
  if (t < 8) {
    int bb = t >> 1, cc2 = t & 1;
    float acc = clsb[cc2];
    for (int kk = 0; kk < DMODEL; kk++)
      acc = fmaf(pooled[bb * DMODEL + kk], clsW[kk * 2 + cc2], acc);
    lg[t] = acc;
  }
  __syncthreads();
  if (t < 16) {
    float acc = mcb[t];
    for (int i = 0; i < 8; i++) acc = fmaf(lg[i], mcW[i * 16 + t], acc);
    o16[t] = acc;
  }
  __syncthreads();
  if (t == 0) {
    float mx = o16[0];
    for (int i = 1; i < 16; i++) mx = fmaxf(mx, o16[i]);
    float sum = 0.f;
    float e[16];
    for (int i = 0; i < 16; i++) { e[i] = expf(o16[i] - mx); sum += e[i]; }
    for (int i = 0; i < 16; i++) out[i] = e[i] / sum;
  }
}

// ---------------- host launcher ----------------
extern "C" void kernel_launch(void* const* d_in, const int* in_sizes, int n_in,
                              void* d_out, int out_size, void* d_ws, size_t ws_size,
                              hipStream_t stream) {
  (void)in_sizes; (void)n_in; (void)out_size; (void)ws_size;
  const int*   ids      = (const int*)d_in[0];
  const float* amask    = (const float*)d_in[1];
  const float* emb_word = (const float*)d_in[2];
  const float* emb_pos  = (const float*)d_in[3];
  const float* ln_emb_s = (const float*)d_in[4];
  const float* ln_emb_b = (const float*)d_in[5];
  const float* Wq  = (const float*)d_in[6];
  const float* Wk  = (const float*)d_in[7];
  const float* Wv  = (const float*)d_in[8];
  const float* Wqg = (const float*)d_in[9];
  const float* Wkg = (const float*)d_in[10];
  const float* Wvg = (const float*)d_in[11];
  const float* Wo  = (const float*)d_in[12];
  const float* bq  = (const float*)d_in[13];
  const float* bk  = (const float*)d_in[14];
  const float* bv  = (const float*)d_in[15];
  const float* bqg = (const float*)d_in[16];
  const float* bkg = (const float*)d_in[17];
  const float* bvg = (const float*)d_in[18];
  const float* bo  = (const float*)d_in[19];
  const float* ln1_s = (const float*)d_in[20];
  const float* ln1_b = (const float*)d_in[21];
  const float* Wi  = (const float*)d_in[22];
  const float* bi  = (const float*)d_in[23];
  const float* Wf  = (const float*)d_in[24];
  const float* bf_ = (const float*)d_in[25];
  const float* ln2_s = (const float*)d_in[26];
  const float* ln2_b = (const float*)d_in[27];
  const float* pooler_W = (const float*)d_in[28];
  const float* pooler_b = (const float*)d_in[29];
  const float* cls_W = (const float*)d_in[30];
  const float* cls_b = (const float*)d_in[31];
  const float* mc_W  = (const float*)d_in[32];
  const float* mc_b  = (const float*)d_in[33];
  float* out = (float*)d_out;

  float* ws = (float*)d_ws;
  const size_t NT = (size_t)BBATCH * SSEQ;     // 8192 tokens
  const size_t TD = NT * DMODEL;               // 6.29M
  const size_t WDD = (size_t)DMODEL * DMODEL;  // 589824

  float* h  = ws;                    // [NT, D] fp32
  float* Pc = ws + TD;               // fp32 GEMM-out panel
  u16*  ub  = (u16*)(ws + 2 * TD);
  u16* hb   = ub;                    // [NT, D] bf16
  u16* attb = ub + TD;               // [NT, D] bf16
  u16* qkvb = ub + 2 * TD;           // [NT, NQKV] bf16  (5*TD)
  u16* midb = ub + 7 * TD;           // [NT, DFF] bf16   (4*TD)
  u16* wt   = ub + 11 * TD;          // per-layer weights: 14*WDD u16
  u16* wqkvT = wt;                   // [NQKV, D]
  u16* woT   = wt + 5 * WDD;         // [D, D]
  u16* wiT   = wt + 6 * WDD;         // [DFF, D] (4 WDD)
  u16* wfT   = wt + 10 * WDD;        // [D, DFF] (4 WDD)
  float* fbias  = (float*)(wt + 14 * WDD);       // [L, NQKV]
  float* qgb    = fbias + NLAYER * NQKV;         // [B, D]
  float* pooled = qgb + BBATCH * DMODEL;         // [B, D]

  embed_ln_kernel<<<(int)NT, 256, 0, stream>>>(ids, emb_word, emb_pos,
                                               ln_emb_s, ln_emb_b, h, hb);
  bias_cat_kernel<<<(NLAYER * NQKV + 255) / 256, 256, 0, stream>>>(bq, bk, bv, bkg, bvg, fbias);

  dim3 gQKV(NT / 128, NQKV / 128);     // (64, 30)
  dim3 gDD(NT / 128, DMODEL / 128);    // (64, 6)
  dim3 gF1(NT / 128, DFFN / 128);      // (64, 24)
  dim3 c6(DMODEL / 64, DMODEL / 64, 6);
  dim3 cWi(DMODEL / 64, DFFN / 64);    // (12, 48)
  dim3 cWf(DFFN / 64, DMODEL / 64);    // (48, 12)

  for (int l = 0; l < NLAYER; l++) {
    const size_t wd = (size_t)l * WDD;
    convt6_kernel<<<c6, 256, 0, stream>>>(Wq + wd, Wk + wd, Wv + wd,
                                          Wkg + wd, Wvg + wd, Wo + wd, wt);
    convt_kernel<<<cWi, 256, 0, stream>>>(Wi + (size_t)l * DMODEL * DFFN, wiT, DMODEL, DFFN);
    convt_kernel<<<cWf, 256, 0, stream>>>(Wf + (size_t)l * DMODEL * DFFN, wfT, DFFN, DMODEL);

    // fused q|k|v|kg|vg projection -> bf16 panel
    mfma_gemm_kernel<2><<<gQKV, 256, 0, stream>>>(hb, wqkvT, fbias + (size_t)l * NQKV,
                                                  (float*)nullptr, qkvb, (int)NT, NQKV, DMODEL);
    local_attn_kernel<<<BBATCH * NHEAD * 8 * 8, 256, 0, stream>>>(qkvb, amask, attb);
    rowvec_mat_kernel<<<BBATCH * 3, 256, 0, stream>>>(h, (size_t)SSEQ * DMODEL,
        Wqg + wd, bqg + l * DMODEL, qgb, DMODEL, DMODEL, QSCALE, 0);
    global_attn_kernel<<<BBATCH * NHEAD, 256, 0, stream>>>(qgb, qkvb, amask, attb);
    // output projection + residual LN
    mfma_gemm_kernel<0><<<gDD, 256, 0, stream>>>(attb, woT, bo + l * DMODEL, Pc,
                                                 (u16*)nullptr, (int)NT, DMODEL, DMODEL);
    add_ln_kernel<<<(int)NT, 256, 0, stream>>>(h, Pc, ln1_s + l * DMODEL, ln1_b + l * DMODEL, hb);
    // FFN
    mfma_gemm_kernel<1><<<gF1, 256, 0, stream>>>(hb, wiT, bi + l * DFFN,
                                                 (float*)nullptr, midb, (int)NT, DFFN, DMODEL);
    mfma_gemm_kernel<0><<<gDD, 256, 0, stream>>>(midb, wfT, bf_ + l * DMODEL, Pc,
                                                 (u16*)nullptr, (int)NT, DMODEL, DFFN);
    add_ln_kernel<<<(int)NT, 256, 0, stream>>>(h, Pc, ln2_s + l * DMODEL, ln2_b + l * DMODEL, hb);
  }

  rowvec_mat_kernel<<<BBATCH * 3, 256, 0, stream>>>(h, (size_t)SSEQ * DMODEL,
      pooler_W, pooler_b, pooled, DMODEL, DMODEL, 1.0f, 1);
  head_kernel<<<1, 256, 0, stream>>>(pooled, cls_W, cls_b, mc_W, mc_b, out);
}